// Round 5
// baseline (257.479 us; speedup 1.0000x reference)
//
#include <hip/hip_runtime.h>

typedef __bf16 bf16_t;
typedef bf16_t bf16x8 __attribute__((ext_vector_type(8)));
typedef float f32x4 __attribute__((ext_vector_type(4)));
typedef unsigned short u16;
typedef unsigned int u32;

#define E_TOT 524288
#define MT 128
#define NBLK (E_TOT / MT)

// round-to-nearest-even f32 -> bf16 (prep kernels)
__device__ __forceinline__ u16 f2bf(float f) {
  u32 u = __builtin_bit_cast(u32, f);
  u += 0x7FFFu + ((u >> 16) & 1u);
  return (u16)(u >> 16);
}

__device__ __forceinline__ bf16x8 pack8(f32x4 a, f32x4 b) {
  bf16x8 p;
  p[0] = (bf16_t)a[0]; p[1] = (bf16_t)a[1]; p[2] = (bf16_t)a[2]; p[3] = (bf16_t)a[3];
  p[4] = (bf16_t)b[0]; p[5] = (bf16_t)b[1]; p[6] = (bf16_t)b[2]; p[7] = (bf16_t)b[3];
  return p;
}

__device__ __forceinline__ void gload_lds16(const void* g, void* l) {
  __builtin_amdgcn_global_load_lds(
      (const __attribute__((address_space(1))) u32*)g,
      (__attribute__((address_space(3))) u32*)l, 16, 0, 0);
}

// W1 [384][256] f32 -> chunked+inverse-swizzled bf16 for linear global_load_lds.
// 16-B unit U = kb*2048 + n*8 + jswz holds W1^T[n][kb*64 + ((jswz^(n&7))*8) .. +8)
__global__ void prep_w1ts(const float* __restrict__ W1, u16* __restrict__ W1Ts) {
  int t = blockIdx.x * 256 + threadIdx.x;  // 0..98303
  if (t < 384 * 256) {
    int U = t >> 3, e = t & 7;
    int kb = U >> 11, rem = U & 2047;
    int n = rem >> 3, jswz = rem & 7;
    int k = kb * 64 + ((jswz ^ (n & 7)) << 3) + e;
    W1Ts[t] = f2bf(W1[k * 256 + n]);
  }
}

// W2 [256][64] f32 -> inverse-swizzled W2^T bf16 ("chunk 6", 32 KB).
// 16-B unit U = n*32 + uj holds W2^T[n][((uj^(n&7))*8) .. +8)
__global__ void prep_w2ts(const float* __restrict__ W2, u16* __restrict__ W2Ts) {
  int t = blockIdx.x * 256 + threadIdx.x;  // 0..16383
  if (t < 64 * 256) {
    int U = t >> 3, e = t & 7;
    int n = U >> 5, uj = U & 31;
    int k = ((uj ^ (n & 7)) << 3) + e;
    W2Ts[t] = f2bf(W2[k * 64 + n]);
  }
}

// Fused: x = [src|dest|edge|u[batch]] (E x 384); h = relu(x@W1+b1); out = h@W2+b2
__global__ void __launch_bounds__(512) edge_fused(
    const float* __restrict__ src, const float* __restrict__ dst,
    const float* __restrict__ ea, const float* __restrict__ u,
    const int* __restrict__ batch, const u16* __restrict__ Wall,
    const float* __restrict__ b1, const float* __restrict__ b2,
    float* __restrict__ out)
{
  // 81920 B LDS: As[128][64]swz @0 (8192 u16), Wb0 @8192 (16384), Wb1 @24576 (16384)
  // epilogue overlays: W2s = Wb0 (staged as chunk 6), Hs(half) = Wb1
  __shared__ __align__(16) u16 smem[40960];
  u16* As  = smem;
  u16* Wb0 = smem + 8192;
  u16* Wb1 = smem + 24576;
  u16* W2s = Wb0;
  u16* Hs  = Wb1;

  const int t    = threadIdx.x;
  const int wid  = t >> 6;
  const int lane = t & 63;
  const int lr   = lane & 15;
  const int lg   = lane >> 4;
  const int wr   = wid >> 2;      // 0..1 : 64-row half of M-tile
  const int wc   = wid & 3;       // 0..3 : 64-col slice of HIDDEN
  const int e0   = blockIdx.x * MT;
  const int r    = t >> 2;        // A row owned by this thread (0..127)
  const int cg   = (t & 3) << 4;  // A col base {0,16,32,48}
  const int j0   = (t & 3) * 2;   // As 16B-unit base

  auto issueA = [&](int c, f32x4* av) {
    const float* rowp;
    if (c < 2)       rowp = src + (size_t)(e0 + r) * 128 + c * 64;
    else if (c < 4)  rowp = dst + (size_t)(e0 + r) * 128 + (c - 2) * 64;
    else if (c == 4) rowp = ea + (size_t)(e0 + r) * 64;
    else             rowp = u + (size_t)batch[e0 + r] * 64;
    av[0] = *(const f32x4*)(rowp + cg + 0);
    av[1] = *(const f32x4*)(rowp + cg + 4);
    av[2] = *(const f32x4*)(rowp + cg + 8);
    av[3] = *(const f32x4*)(rowp + cg + 12);
  };
  auto stageW = [&](int chunk, u16* Wn) {
    #pragma unroll
    for (int it = 0; it < 4; ++it) {
      int ubase = (it * 8 + wid) * 64;   // wave-uniform
      gload_lds16(Wall + ((size_t)chunk * 2048 + ubase + lane) * 8, &Wn[ubase * 8]);
    }
  };

  // ---- prologue: A chunks 0,1 + W chunk 0 in flight ----
  f32x4 avA[4], avB[4];
  issueA(0, avA);
  issueA(1, avB);
  stageW(0, Wb0);

  f32x4 acc[4][4];
  #pragma unroll
  for (int i = 0; i < 4; ++i)
    #pragma unroll
    for (int j = 0; j < 4; ++j)
      acc[i][j] = (f32x4){0.f, 0.f, 0.f, 0.f};

  // ---- K loop: 6 chunks of 64 ----
  #pragma unroll
  for (int kb = 0; kb < 6; ++kb) {
    u16* Wc = (kb & 1) ? Wb1 : Wb0;   // compute buffer (chunk kb)
    u16* Wn = (kb & 1) ? Wb0 : Wb1;   // stage buffer (chunk kb+1; kb=5 -> W2s)
    f32x4* av = (kb & 1) ? avB : avA; // holds chunk kb (compiler inserts the A-wait)

    // S-phase: pack+write As(kb); stage W(kb+1)
    {
      bf16x8 lo = pack8(av[0], av[1]);
      bf16x8 hi = pack8(av[2], av[3]);
      *(bf16x8*)&As[r * 64 + ((j0 ^ (r & 7)) << 3)]       = lo;
      *(bf16x8*)&As[r * 64 + (((j0 + 1) ^ (r & 7)) << 3)] = hi;
    }
    stageW(kb + 1, Wn);   // chunk 6 == W2Ts (appended after W1Ts in d_ws)

    // drain W(kb) only: newer in flight = A(kb+1)+W(kb+1) = 8 (kb<5) or W2s = 4 (kb=5)
    if (kb < 5) asm volatile("s_waitcnt vmcnt(8) lgkmcnt(0)" ::: "memory");
    else        asm volatile("s_waitcnt vmcnt(4) lgkmcnt(0)" ::: "memory");
    __builtin_amdgcn_sched_barrier(0);
    __builtin_amdgcn_s_barrier();

    // C-phase: issue A(kb+2) into the just-freed buffer, then MFMA
    if (kb < 4) issueA(kb + 2, av);

    __builtin_amdgcn_s_setprio(1);
    #pragma unroll
    for (int ks = 0; ks < 2; ++ks) {
      bf16x8 af[4];
      #pragma unroll
      for (int mf = 0; mf < 4; ++mf) {
        int row = wr * 64 + mf * 16 + lr;
        af[mf] = *(const bf16x8*)&As[row * 64 + (((ks * 4 + lg) ^ (row & 7)) << 3)];
      }
      #pragma unroll
      for (int nf = 0; nf < 4; ++nf) {
        int n = wc * 64 + nf * 16 + lr;
        bf16x8 bfr = *(const bf16x8*)&Wc[n * 64 + (((ks * 4 + lg) ^ (n & 7)) << 3)];
        #pragma unroll
        for (int mf = 0; mf < 4; ++mf)
          acc[mf][nf] = __builtin_amdgcn_mfma_f32_16x16x32_bf16(af[mf], bfr, acc[mf][nf], 0, 0, 0);
      }
    }
    __builtin_amdgcn_s_setprio(0);
    __builtin_amdgcn_s_barrier();   // chunk kb LDS reads done before next S overwrites
  }

  asm volatile("s_waitcnt vmcnt(0)" ::: "memory");  // W2s landed in Wb0

  float bias1[4];
  #pragma unroll
  for (int nf = 0; nf < 4; ++nf) bias1[nf] = b1[wc * 64 + nf * 16 + lr];

  // layer-2 wave assignment: 16 frags of a 64x64 out tile, 2 per wave
  const int mf2  = wid >> 1;
  const int nf2a = (wid & 1) * 2;
  const int nf2b = nf2a + 1;
  const float bb_a = b2[nf2a * 16 + lr];
  const float bb_b = b2[nf2b * 16 + lr];
  const int rowA = mf2 * 16 + lr;

  #pragma unroll
  for (int half = 0; half < 2; ++half) {
    // waves owning this row-half write h = relu(acc+b1) -> Hs (swizzled [64][256])
    if (wr == half) {
      #pragma unroll
      for (int mf = 0; mf < 4; ++mf)
        #pragma unroll
        for (int nf = 0; nf < 4; ++nf)
          #pragma unroll
          for (int rr = 0; rr < 4; ++rr) {
            int row = mf * 16 + lg * 4 + rr;          // 0..63 within half
            int col = wc * 64 + nf * 16 + lr;
            float v = fmaxf(acc[mf][nf][rr] + bias1[nf], 0.f);
            *(bf16_t*)&Hs[row * 256 + ((((col >> 3) ^ (row & 7)) << 3) | (col & 7))] = (bf16_t)v;
          }
    }
    __syncthreads();

    // layer 2 for this half: all 8 waves, 2 frags each
    f32x4 acc2a = (f32x4){0.f, 0.f, 0.f, 0.f};
    f32x4 acc2b = (f32x4){0.f, 0.f, 0.f, 0.f};
    #pragma unroll
    for (int ks = 0; ks < 8; ++ks) {
      bf16x8 a = *(const bf16x8*)&Hs[rowA * 256 + (((ks * 4 + lg) ^ (rowA & 7)) << 3)];
      int nA = nf2a * 16 + lr;
      int nB = nf2b * 16 + lr;
      bf16x8 ba = *(const bf16x8*)&W2s[nA * 256 + (((ks * 4 + lg) ^ (nA & 7)) << 3)];
      bf16x8 bb = *(const bf16x8*)&W2s[nB * 256 + (((ks * 4 + lg) ^ (nB & 7)) << 3)];
      acc2a = __builtin_amdgcn_mfma_f32_16x16x32_bf16(a, ba, acc2a, 0, 0, 0);
      acc2b = __builtin_amdgcn_mfma_f32_16x16x32_bf16(a, bb, acc2b, 0, 0, 0);
    }

    #pragma unroll
    for (int rr = 0; rr < 4; ++rr) {
      int row = e0 + half * 64 + mf2 * 16 + lg * 4 + rr;
      out[(size_t)row * 64 + nf2a * 16 + lr] = acc2a[rr] + bb_a;
      out[(size_t)row * 64 + nf2b * 16 + lr] = acc2b[rr] + bb_b;
    }
    __syncthreads();  // Hs reads done before next half overwrites
  }
}

extern "C" void kernel_launch(void* const* d_in, const int* in_sizes, int n_in,
                              void* d_out, int out_size, void* d_ws, size_t ws_size,
                              hipStream_t stream) {
  const float* src  = (const float*)d_in[0];
  const float* dst  = (const float*)d_in[1];
  const float* ea   = (const float*)d_in[2];
  const float* u    = (const float*)d_in[3];
  const int* batch  = (const int*)d_in[4];
  const float* W1   = (const float*)d_in[5];
  const float* b1   = (const float*)d_in[6];
  const float* W2   = (const float*)d_in[7];
  const float* b2   = (const float*)d_in[8];
  float* out = (float*)d_out;

  u16* W1Ts = (u16*)d_ws;            // 6 chunks x 16384 u16 (chunked+swizzled W1^T)
  u16* W2Ts = W1Ts + 384 * 256;      // "chunk 6": 16384 u16 (swizzled W2^T)

  prep_w1ts<<<(384 * 256 + 255) / 256, 256, 0, stream>>>(W1, W1Ts);
  prep_w2ts<<<(64 * 256 + 255) / 256, 256, 0, stream>>>(W2, W2Ts);
  edge_fused<<<NBLK, 512, 0, stream>>>(src, dst, ea, u, batch, W1Ts, b1, b2, out);
}